// Round 3
// baseline (108.893 us; speedup 1.0000x reference)
//
#include <hip/hip_runtime.h>
#include <stdint.h>

#define NBATCH 256
#define NQ 900
#define NC 91
#define NQC (NQ * NC)      // 81900
#define NV4 (NQC / 4)      // 20475
#define KSEL 100
#define IOU_THRF 0.7f
#define CONF_THRF 0.3f

// ---- kernel A (local top-100 per slice) ----
#define ABLK 9             // blocks per batch
#define AV4 2275           // float4 per block slice (9*2275 = 20475 exact)
#define ANT 256
#define ABINS 4096
#define ACH (ABINS / ANT)  // 16
#define ACAP 512

// ---- kernel B (merge + NMS) ----
#define BNT 512
#define BM (ABLK * KSEL)   // 900
#define BP 1024

// monotone key: ascending uint order == ascending float order
__device__ __forceinline__ uint32_t fkey(float x) {
  uint32_t b = __float_as_uint(x);
  return b ^ ((uint32_t)((int32_t)b >> 31) | 0x80000000u);
}

__device__ __forceinline__ float sigmoidf_ref(float x) {
  return 1.0f / (1.0f + expf(-x));
}

// ======================= kernel A =======================
// Each block: local 4096-bin hist of its 9100-logit slice -> local cut ->
// collect candidates (>= cut-1 bin, tie-safe) -> sigmoid -> sort by
// (prob desc, idx asc) -> write exactly local top-100 keys.
__global__ __launch_bounds__(ANT) void kselect(const float* __restrict__ logits,
                                               unsigned long long* __restrict__ cand) {
  __shared__ uint32_t hist[ABINS];
  __shared__ unsigned long long cnd[ACAP];
  __shared__ uint32_t suf[ANT];
  __shared__ uint32_t s_cut, s_c1;
  __shared__ uint32_t pos_ctr;

  const int blk = blockIdx.x;
  const int b = blk / ABLK;
  const int s = blk - b * ABLK;
  const int tid = threadIdx.x;
  const float4* lg4 = (const float4*)(logits + (size_t)b * NQC) + (size_t)s * AV4;

  for (int i = tid; i < ABINS; i += ANT) hist[i] = 0;
  __syncthreads();

  // pass 1: histogram (HBM read)
  for (int i = tid; i < AV4; i += ANT) {
    float4 v = lg4[i];
    atomicAdd(&hist[fkey(v.x) >> 20], 1u);
    atomicAdd(&hist[fkey(v.y) >> 20], 1u);
    atomicAdd(&hist[fkey(v.z) >> 20], 1u);
    atomicAdd(&hist[fkey(v.w) >> 20], 1u);
  }
  __syncthreads();

  // suffix scan over 256 chunk sums to locate local cut bin
  uint32_t mine = 0;
  {
    const int base = tid * ACH;
    #pragma unroll
    for (int i = 0; i < ACH; i++) mine += hist[base + i];
    suf[tid] = mine;
  }
  __syncthreads();
  for (int off = 1; off < ANT; off <<= 1) {
    uint32_t v = suf[tid];
    if (tid + off < ANT) v += suf[tid + off];
    __syncthreads();
    suf[tid] = v;
    __syncthreads();
  }
  {
    uint32_t after = suf[tid] - mine;       // total in strictly-higher chunks
    if (after < KSEL && after + mine >= KSEL) {   // exactly one thread
      uint32_t run = after;
      const int base = tid * ACH;
      for (int i = ACH - 1; i >= 0; i--) {
        uint32_t h = hist[base + i];
        if (run + h >= KSEL) { s_cut = (uint32_t)(base + i); s_c1 = run + h; break; }
        run += h;
      }
    }
  }
  __syncthreads();
  const uint32_t cut = s_cut;
  const uint32_t c1 = s_c1;                 // count in bins >= cut (>= 100)
  const uint32_t below = (cut > 0) ? hist[cut - 1] : 0;
  // tie-safety: include one bin below the cut when it fits
  const uint32_t lobin = (cut > 0 && c1 + below <= ACAP) ? (cut - 1) : cut;
  if (tid == 0) pos_ctr = 0;
  __syncthreads();

  // pass 2: collect (L2-hot re-read); sigmoid only for candidates
  for (int i = tid; i < AV4; i += ANT) {
    float4 v = lg4[i];
    float xs[4] = {v.x, v.y, v.z, v.w};
    #pragma unroll
    for (int c = 0; c < 4; c++) {
      uint32_t k = fkey(xs[c]);
      if ((k >> 20) >= lobin) {
        uint32_t pbits = __float_as_uint(sigmoidf_ref(xs[c]));
        uint32_t pos = atomicAdd(&pos_ctr, 1u);
        if (pos < ACAP) {
          uint32_t idx = (uint32_t)(((s * AV4 + i) << 2) + c);   // idx within batch
          cnd[pos] = (((unsigned long long)(~pbits)) << 32) | (unsigned long long)idx;
        }
      }
    }
  }
  __syncthreads();
  const uint32_t n = pos_ctr < ACAP ? pos_ctr : ACAP;   // n >= 100 always
  uint32_t P = 128;
  while (P < n) P <<= 1;                                // <= 512
  for (uint32_t i = n + tid; i < P; i += ANT) cnd[i] = ~0ULL;
  __syncthreads();

  // bitonic sort ascending: key = (~prob_bits)<<32 | idx
  for (uint32_t kk = 2; kk <= P; kk <<= 1) {
    for (uint32_t jj = kk >> 1; jj > 0; jj >>= 1) {
      for (uint32_t i = tid; i < P; i += ANT) {
        uint32_t ixj = i ^ jj;
        if (ixj > i) {
          unsigned long long a = cnd[i];
          unsigned long long c = cnd[ixj];
          bool sw = ((i & kk) == 0) ? (a > c) : (a < c);
          if (sw) { cnd[i] = c; cnd[ixj] = a; }
        }
      }
      __syncthreads();
    }
  }

  // write exactly local top-100
  if (tid < KSEL)
    cand[((size_t)b * ABLK + s) * KSEL + tid] = cnd[tid];
}

// ======================= kernel B =======================
union BSMem {
  unsigned long long srt[BP];          // 8 KB
  struct {
    float iou[KSEL * KSEL];            // 40 KB
    float box[KSEL][4];
    int keep[KSEL];
  } nms;
};

__global__ __launch_bounds__(BNT) void merge_nms(const unsigned long long* __restrict__ cand,
                                                 const float* __restrict__ pboxes,
                                                 const float* __restrict__ tsizes,
                                                 float* __restrict__ out) {
  __shared__ BSMem sm;
  const int b = blockIdx.x;
  const int tid = threadIdx.x;

  for (int i = tid; i < BP; i += BNT)
    sm.srt[i] = (i < BM) ? cand[(size_t)b * BM + i] : ~0ULL;
  __syncthreads();

  // bitonic sort 1024 ascending (prob desc, idx asc)
  for (uint32_t kk = 2; kk <= BP; kk <<= 1) {
    for (uint32_t jj = kk >> 1; jj > 0; jj >>= 1) {
      for (uint32_t i = tid; i < BP; i += BNT) {
        uint32_t ixj = i ^ jj;
        if (ixj > i) {
          unsigned long long a = sm.srt[i];
          unsigned long long c = sm.srt[ixj];
          bool sw = ((i & kk) == 0) ? (a > c) : (a < c);
          if (sw) { sm.srt[i] = c; sm.srt[ixj] = a; }
        }
      }
      __syncthreads();
    }
  }

  float score = 0.0f;
  int idx = 0;
  if (tid < KSEL) {
    unsigned long long key = sm.srt[tid];
    score = __uint_as_float(~(uint32_t)(key >> 32));
    idx = (int)(uint32_t)(key & 0xFFFFFFFFu);
  }
  __syncthreads();   // all reads of srt done before nms union reuse

  const float img_h = tsizes[b * 2 + 0];
  const float img_w = tsizes[b * 2 + 1];
  float* out_scores = out;
  float* out_labels = out + (size_t)NBATCH * KSEL;
  float* out_boxes  = out + (size_t)2 * NBATCH * KSEL;
  float* out_keep   = out + (size_t)2 * NBATCH * KSEL + (size_t)NBATCH * KSEL * 4;

  if (tid < KSEL) {
    int q = idx / NC;
    int lab = idx - q * NC;
    const float* pb = pboxes + ((size_t)b * NQ + q) * 4;
    float cx = pb[0], cy = pb[1], w = pb[2], h = pb[3];
    float hw = __fmul_rn(0.5f, w), hh = __fmul_rn(0.5f, h);
    float x0 = __fmul_rn(__fsub_rn(cx, hw), img_w);
    float y0 = __fmul_rn(__fsub_rn(cy, hh), img_h);
    float x1 = __fmul_rn(__fadd_rn(cx, hw), img_w);
    float y1 = __fmul_rn(__fadd_rn(cy, hh), img_h);
    out_scores[(size_t)b * KSEL + tid] = score;
    out_labels[(size_t)b * KSEL + tid] = (float)lab;
    float* ob = out_boxes + ((size_t)b * KSEL + tid) * 4;
    ob[0] = x0; ob[1] = y0; ob[2] = x1; ob[3] = y1;
    sm.nms.box[tid][0] = x0; sm.nms.box[tid][1] = y0;
    sm.nms.box[tid][2] = x1; sm.nms.box[tid][3] = y1;
  }
  __syncthreads();

  for (int e = tid; e < KSEL * KSEL; e += BNT) {
    int i = e / KSEL;
    int j = e - i * KSEL;
    float ax0 = sm.nms.box[i][0], ay0 = sm.nms.box[i][1];
    float ax1 = sm.nms.box[i][2], ay1 = sm.nms.box[i][3];
    float bx0 = sm.nms.box[j][0], by0 = sm.nms.box[j][1];
    float bx1 = sm.nms.box[j][2], by1 = sm.nms.box[j][3];
    float areaA = __fmul_rn(__fsub_rn(ax1, ax0), __fsub_rn(ay1, ay0));
    float areaB = __fmul_rn(__fsub_rn(bx1, bx0), __fsub_rn(by1, by0));
    float ltx = fmaxf(ax0, bx0), lty = fmaxf(ay0, by0);
    float rbx = fminf(ax1, bx1), rby = fminf(ay1, by1);
    float wx = fmaxf(__fsub_rn(rbx, ltx), 0.0f);
    float wy = fmaxf(__fsub_rn(rby, lty), 0.0f);
    float inter = __fmul_rn(wx, wy);
    float uni = __fsub_rn(__fadd_rn(areaA, areaB), inter);
    sm.nms.iou[e] = __fdiv_rn(inter, fmaxf(uni, 1e-9f));
  }
  __syncthreads();

  // sequential NMS inside wave 0 (shfl, no block barriers)
  if (tid < 64) {
    int keepA = 1;
    int keepB = 1;
    for (int i = 0; i < KSEL; i++) {
      int owner = i & 63;
      int ki = (i < 64) ? __shfl(keepA, owner) : __shfl(keepB, owner);
      if (ki) {
        if (tid > i && sm.nms.iou[i * KSEL + tid] > IOU_THRF) keepA = 0;
        int j = tid + 64;
        if (j < KSEL && j > i && sm.nms.iou[i * KSEL + j] > IOU_THRF) keepB = 0;
      }
    }
    sm.nms.keep[tid] = keepA;
    if (tid + 64 < KSEL) sm.nms.keep[tid + 64] = keepB;
  }
  __syncthreads();

  if (tid < KSEL) {
    float kp = (score > CONF_THRF && sm.nms.keep[tid]) ? 1.0f : 0.0f;
    out_keep[(size_t)b * KSEL + tid] = kp;
  }
}

// ======================= fallback: R2 monolithic (known-passing) =======================
#define NBINS 8192
#define NT 1024
#define CHUNK (NBINS / NT)
#define CAP 1024

union MSMem {
  struct {
    uint32_t hist[NBINS];
    unsigned long long cand[CAP];
  } sel;
  struct {
    float iou[KSEL * KSEL];
    float box[KSEL][4];
    int keep[KSEL];
  } nms;
};

__global__ __launch_bounds__(NT) void postproc_mono(const float* __restrict__ logits,
                                                    const float* __restrict__ pboxes,
                                                    const float* __restrict__ tsizes,
                                                    float* __restrict__ out) {
  __shared__ MSMem sm;
  __shared__ uint32_t suf[NT];
  __shared__ uint32_t s_cut, s_above, s_cnt, s_lobin, s_cut2;
  __shared__ uint32_t cand_cnt;

  const int b = blockIdx.x;
  const int tid = threadIdx.x;
  const float4* lg4 = (const float4*)(logits + (size_t)b * NQC);

  for (int i = tid; i < NBINS; i += NT) sm.sel.hist[i] = 0;
  __syncthreads();
  for (int i = tid; i < NV4; i += NT) {
    float4 v = lg4[i];
    atomicAdd(&sm.sel.hist[fkey(v.x) >> 19], 1u);
    atomicAdd(&sm.sel.hist[fkey(v.y) >> 19], 1u);
    atomicAdd(&sm.sel.hist[fkey(v.z) >> 19], 1u);
    atomicAdd(&sm.sel.hist[fkey(v.w) >> 19], 1u);
  }
  __syncthreads();

  uint32_t mine;
  {
    uint32_t s = 0;
    const int base = tid * CHUNK;
    #pragma unroll
    for (int i = 0; i < CHUNK; i++) s += sm.sel.hist[base + i];
    mine = s;
    suf[tid] = s;
  }
  __syncthreads();
  for (int off = 1; off < NT; off <<= 1) {
    uint32_t v = suf[tid];
    if (tid + off < NT) v += suf[tid + off];
    __syncthreads();
    suf[tid] = v;
    __syncthreads();
  }
  {
    uint32_t after = suf[tid] - mine;
    if (after < KSEL && after + mine >= KSEL) {
      uint32_t run = after;
      const int base = tid * CHUNK;
      for (int i = CHUNK - 1; i >= 0; i--) {
        uint32_t h = sm.sel.hist[base + i];
        if (run + h >= KSEL) {
          uint32_t cut = (uint32_t)(base + i);
          uint32_t below = (cut > 0) ? sm.sel.hist[cut - 1] : 0;
          s_cut = cut; s_above = run; s_cnt = h;
          s_lobin = (cut > 0 && run + h + below <= CAP) ? cut - 1 : cut;
          break;
        }
        run += h;
      }
    }
  }
  __syncthreads();
  const uint32_t cut1 = s_cut;
  const uint32_t lobin = s_lobin;
  const bool need2 = (s_above + s_cnt > CAP);
  uint32_t cut2 = 0;

  if (need2) {
    const uint32_t above0 = s_above;
    __syncthreads();
    for (int i = tid; i < NBINS; i += NT) sm.sel.hist[i] = 0;
    __syncthreads();
    for (int i = tid; i < NV4; i += NT) {
      float4 v = lg4[i];
      float xs[4] = {v.x, v.y, v.z, v.w};
      #pragma unroll
      for (int c = 0; c < 4; c++) {
        uint32_t k = fkey(xs[c]);
        if ((k >> 19) == cut1) atomicAdd(&sm.sel.hist[(k >> 6) & 0x1FFFu], 1u);
      }
    }
    __syncthreads();
    {
      uint32_t s = 0;
      const int base = tid * CHUNK;
      #pragma unroll
      for (int i = 0; i < CHUNK; i++) s += sm.sel.hist[base + i];
      mine = s;
      suf[tid] = s;
    }
    __syncthreads();
    for (int off = 1; off < NT; off <<= 1) {
      uint32_t v = suf[tid];
      if (tid + off < NT) v += suf[tid + off];
      __syncthreads();
      suf[tid] = v;
      __syncthreads();
    }
    {
      uint32_t after = above0 + (suf[tid] - mine);
      if (after < KSEL && after + mine >= KSEL) {
        uint32_t run = after;
        const int base = tid * CHUNK;
        for (int i = CHUNK - 1; i >= 0; i--) {
          uint32_t h = sm.sel.hist[base + i];
          if (run + h >= KSEL) { s_cut2 = (uint32_t)(base + i); break; }
          run += h;
        }
      }
    }
    __syncthreads();
    cut2 = s_cut2;
  }

  if (tid == 0) cand_cnt = 0;
  __syncthreads();
  for (int i = tid; i < NV4; i += NT) {
    float4 v = lg4[i];
    float xs[4] = {v.x, v.y, v.z, v.w};
    #pragma unroll
    for (int c = 0; c < 4; c++) {
      uint32_t k = fkey(xs[c]);
      uint32_t b1 = k >> 19;
      bool sel = need2 ? (b1 > cut1 || (b1 == cut1 && ((k >> 6) & 0x1FFFu) >= cut2))
                       : (b1 >= lobin);
      if (sel) {
        uint32_t pbits = __float_as_uint(sigmoidf_ref(xs[c]));
        uint32_t pos = atomicAdd(&cand_cnt, 1u);
        if (pos < CAP)
          sm.sel.cand[pos] = (((unsigned long long)(~pbits)) << 32) |
                             (unsigned long long)(uint32_t)(4 * i + c);
      }
    }
  }
  __syncthreads();
  const uint32_t n = cand_cnt < CAP ? cand_cnt : CAP;
  uint32_t P = 1;
  while (P < n) P <<= 1;
  for (uint32_t i = n + tid; i < P; i += NT) sm.sel.cand[i] = ~0ULL;
  __syncthreads();

  for (uint32_t kk = 2; kk <= P; kk <<= 1) {
    for (uint32_t jj = kk >> 1; jj > 0; jj >>= 1) {
      for (uint32_t i = tid; i < P; i += NT) {
        uint32_t ixj = i ^ jj;
        if (ixj > i) {
          unsigned long long a = sm.sel.cand[i];
          unsigned long long c = sm.sel.cand[ixj];
          bool sw = ((i & kk) == 0) ? (a > c) : (a < c);
          if (sw) { sm.sel.cand[i] = c; sm.sel.cand[ixj] = a; }
        }
      }
      __syncthreads();
    }
  }

  float score = 0.0f;
  int idx = 0;
  if (tid < KSEL) {
    unsigned long long key = sm.sel.cand[tid];
    score = __uint_as_float(~(uint32_t)(key >> 32));
    idx = (int)(uint32_t)(key & 0xFFFFFFFFu);
  }
  __syncthreads();

  const float img_h = tsizes[b * 2 + 0];
  const float img_w = tsizes[b * 2 + 1];
  float* out_scores = out;
  float* out_labels = out + (size_t)NBATCH * KSEL;
  float* out_boxes  = out + (size_t)2 * NBATCH * KSEL;
  float* out_keep   = out + (size_t)2 * NBATCH * KSEL + (size_t)NBATCH * KSEL * 4;

  if (tid < KSEL) {
    int q = idx / NC;
    int lab = idx - q * NC;
    const float* pb = pboxes + ((size_t)b * NQ + q) * 4;
    float cx = pb[0], cy = pb[1], w = pb[2], h = pb[3];
    float hw = __fmul_rn(0.5f, w), hh = __fmul_rn(0.5f, h);
    float x0 = __fmul_rn(__fsub_rn(cx, hw), img_w);
    float y0 = __fmul_rn(__fsub_rn(cy, hh), img_h);
    float x1 = __fmul_rn(__fadd_rn(cx, hw), img_w);
    float y1 = __fmul_rn(__fadd_rn(cy, hh), img_h);
    out_scores[(size_t)b * KSEL + tid] = score;
    out_labels[(size_t)b * KSEL + tid] = (float)lab;
    float* ob = out_boxes + ((size_t)b * KSEL + tid) * 4;
    ob[0] = x0; ob[1] = y0; ob[2] = x1; ob[3] = y1;
    sm.nms.box[tid][0] = x0; sm.nms.box[tid][1] = y0;
    sm.nms.box[tid][2] = x1; sm.nms.box[tid][3] = y1;
  }
  __syncthreads();

  for (int e = tid; e < KSEL * KSEL; e += NT) {
    int i = e / KSEL;
    int j = e - i * KSEL;
    float ax0 = sm.nms.box[i][0], ay0 = sm.nms.box[i][1];
    float ax1 = sm.nms.box[i][2], ay1 = sm.nms.box[i][3];
    float bx0 = sm.nms.box[j][0], by0 = sm.nms.box[j][1];
    float bx1 = sm.nms.box[j][2], by1 = sm.nms.box[j][3];
    float areaA = __fmul_rn(__fsub_rn(ax1, ax0), __fsub_rn(ay1, ay0));
    float areaB = __fmul_rn(__fsub_rn(bx1, bx0), __fsub_rn(by1, by0));
    float ltx = fmaxf(ax0, bx0), lty = fmaxf(ay0, by0);
    float rbx = fminf(ax1, bx1), rby = fminf(ay1, by1);
    float wx = fmaxf(__fsub_rn(rbx, ltx), 0.0f);
    float wy = fmaxf(__fsub_rn(rby, lty), 0.0f);
    float inter = __fmul_rn(wx, wy);
    float uni = __fsub_rn(__fadd_rn(areaA, areaB), inter);
    sm.nms.iou[e] = __fdiv_rn(inter, fmaxf(uni, 1e-9f));
  }
  __syncthreads();

  if (tid < 64) {
    int keepA = 1;
    int keepB = 1;
    for (int i = 0; i < KSEL; i++) {
      int owner = i & 63;
      int ki = (i < 64) ? __shfl(keepA, owner) : __shfl(keepB, owner);
      if (ki) {
        if (tid > i && sm.nms.iou[i * KSEL + tid] > IOU_THRF) keepA = 0;
        int j = tid + 64;
        if (j < KSEL && j > i && sm.nms.iou[i * KSEL + j] > IOU_THRF) keepB = 0;
      }
    }
    sm.nms.keep[tid] = keepA;
    if (tid + 64 < KSEL) sm.nms.keep[tid + 64] = keepB;
  }
  __syncthreads();

  if (tid < KSEL) {
    float kp = (score > CONF_THRF && sm.nms.keep[tid]) ? 1.0f : 0.0f;
    out_keep[(size_t)b * KSEL + tid] = kp;
  }
}

extern "C" void kernel_launch(void* const* d_in, const int* in_sizes, int n_in,
                              void* d_out, int out_size, void* d_ws, size_t ws_size,
                              hipStream_t stream) {
  const float* logits = (const float*)d_in[0];   // (256, 900, 91) f32
  const float* pboxes = (const float*)d_in[1];   // (256, 900, 4)  f32
  const float* tsizes = (const float*)d_in[2];   // (256, 2)       f32
  (void)in_sizes; (void)n_in; (void)out_size;

  const size_t need = (size_t)NBATCH * ABLK * KSEL * sizeof(unsigned long long); // 1.84 MB
  if (ws_size >= need) {
    unsigned long long* cand = (unsigned long long*)d_ws;
    kselect<<<NBATCH * ABLK, ANT, 0, stream>>>(logits, cand);
    merge_nms<<<NBATCH, BNT, 0, stream>>>(cand, pboxes, tsizes, (float*)d_out);
  } else {
    postproc_mono<<<NBATCH, NT, 0, stream>>>(logits, pboxes, tsizes, (float*)d_out);
  }
}